// Round 1
// baseline (4219.366 us; speedup 1.0000x reference)
//
#include <hip/hip_runtime.h>
#include <cstddef>

#define S_LEN 256
#define H_DIM 512
#define G_DIM 2048
#define B_SZ  4
#define V_SZ  32000

__device__ __forceinline__ float sigf(float x) { return 1.0f / (1.0f + expf(-x)); }

// ---------------- zero init ----------------
__global__ void zero_kernel(float* __restrict__ p, int n4) {
  int i = blockIdx.x * blockDim.x + threadIdx.x;
  if (i < n4) ((float4*)p)[i] = make_float4(0.f, 0.f, 0.f, 0.f);
}

// ---------------- embedding + DyT ----------------
__global__ __launch_bounds__(128)
void embed_dyt(const int* __restrict__ idx, const float* __restrict__ E,
               const float* __restrict__ alpha_p, const float* __restrict__ gamma,
               const float* __restrict__ beta, float* __restrict__ out) {
  const int row = blockIdx.x;          // b*S + s
  const int t4  = threadIdx.x * 4;     // 0..508
  const int id  = idx[row];
  const float al = alpha_p[0];
  float4 e = make_float4(0.f, 0.f, 0.f, 0.f);
  if (id != 0) e = *(const float4*)(E + (size_t)id * H_DIM + t4);
  const float4 g = *(const float4*)(gamma + t4);
  const float4 b = *(const float4*)(beta + t4);
  float4 o;
  o.x = g.x * tanhf(al * e.x) + b.x;
  o.y = g.y * tanhf(al * e.y) + b.y;
  o.z = g.z * tanhf(al * e.z) + b.z;
  o.w = g.w * tanhf(al * e.w) + b.w;
  *(float4*)(out + (size_t)row * H_DIM + t4) = o;
}

// ---------------- GEMM: C[M,N] = A[M,K] @ W[N,K]^T + bias, optional DyT epilogue ----
// EPI==0: C = acc + bias
// EPI==1: C = gamma*tanh(alpha*(acc + bias (+residual))) + beta
template<int EPI>
__global__ __launch_bounds__(256)
void gemm_nt(const float* __restrict__ A, const float* __restrict__ W,
             const float* __restrict__ bias, float* __restrict__ C,
             int N, int K,
             const float* __restrict__ alpha_p, const float* __restrict__ gamma,
             const float* __restrict__ beta, const float* __restrict__ residual) {
  __shared__ float As[8][132];
  __shared__ float Ws[8][132];
  const int bm = blockIdx.x * 128;   // M-dim on x so concurrent blocks share W panel (L2)
  const int bn = blockIdx.y * 128;
  const int tid = threadIdx.x;
  const int tx = tid & 15, ty = tid >> 4;
  float acc[8][8] = {};
  const int i4 = tid * 4;
  const int lm = i4 >> 3;     // 0..127
  const int lk = i4 & 7;      // 0 or 4
  const float* Arow = A + (size_t)(bm + lm) * K + lk;
  const float* Wrow = W + (size_t)(bn + lm) * K + lk;

  for (int k0 = 0; k0 < K; k0 += 8) {
    float4 va = *(const float4*)(Arow + k0);
    float4 vw = *(const float4*)(Wrow + k0);
    As[lk + 0][lm] = va.x; As[lk + 1][lm] = va.y; As[lk + 2][lm] = va.z; As[lk + 3][lm] = va.w;
    Ws[lk + 0][lm] = vw.x; Ws[lk + 1][lm] = vw.y; Ws[lk + 2][lm] = vw.z; Ws[lk + 3][lm] = vw.w;
    __syncthreads();
#pragma unroll
    for (int kk = 0; kk < 8; ++kk) {
      float a[8], w[8];
      *(float4*)(a)     = *(const float4*)&As[kk][ty * 4];
      *(float4*)(a + 4) = *(const float4*)&As[kk][64 + ty * 4];
      *(float4*)(w)     = *(const float4*)&Ws[kk][tx * 4];
      *(float4*)(w + 4) = *(const float4*)&Ws[kk][64 + tx * 4];
#pragma unroll
      for (int ii = 0; ii < 8; ++ii)
#pragma unroll
        for (int jj = 0; jj < 8; ++jj)
          acc[ii][jj] += a[ii] * w[jj];
    }
    __syncthreads();
  }

  float al = 0.f;
  if (EPI == 1) al = alpha_p[0];
#pragma unroll
  for (int ii = 0; ii < 8; ++ii) {
    const int row = bm + ((ii < 4) ? (ty * 4 + ii) : (60 + ty * 4 + ii));
#pragma unroll
    for (int hf = 0; hf < 2; ++hf) {
      const int ncol = bn + hf * 64 + tx * 4;
      float4 v;
      v.x = acc[ii][hf * 4 + 0]; v.y = acc[ii][hf * 4 + 1];
      v.z = acc[ii][hf * 4 + 2]; v.w = acc[ii][hf * 4 + 3];
      const float4 bb = *(const float4*)(bias + ncol);
      v.x += bb.x; v.y += bb.y; v.z += bb.z; v.w += bb.w;
      if (EPI == 1) {
        if (residual) {
          const float4 r = *(const float4*)(residual + (size_t)row * N + ncol);
          v.x += r.x; v.y += r.y; v.z += r.z; v.w += r.w;
        }
        const float4 gg = *(const float4*)(gamma + ncol);
        const float4 be = *(const float4*)(beta + ncol);
        v.x = gg.x * tanhf(al * v.x) + be.x;
        v.y = gg.y * tanhf(al * v.y) + be.y;
        v.z = gg.z * tanhf(al * v.z) + be.z;
        v.w = gg.w * tanhf(al * v.w) + be.w;
      }
      *(float4*)(C + (size_t)row * N + ncol) = v;
    }
  }
}

// ---------------- one SLSTM time step ----------------
struct StepInst {
  const float* xg;      // row (b*S+t)*xg_stride + gate_row
  const float* Whh;     // [2048,512]
  const float* bhh;     // [2048]
  float* c;             // [4,512] in-place
  const float* h_in;    // [4,512]
  float* h_out;         // [4,512]
  float* spk;           // [B*S,512] or nullptr
  const float* thr;     // [512] (unused when spk==nullptr)
  int xg_stride;
};

// grid: 64 blocks per instance (<=2 instances). Block handles 8 h-columns.
__global__ __launch_bounds__(256)
void slstm_step(StepInst I0, StepInst I1, int t) {
  StepInst I = (blockIdx.x < 64) ? I0 : I1;
  const int blk = blockIdx.x & 63;
  const int c0 = blk * 8;
  __shared__ float hs[4 * H_DIM];
  __shared__ float gred[32][4];
  const int tid = threadIdx.x;
  {
    const float4* s4 = (const float4*)I.h_in;
    float4* d4 = (float4*)hs;
    d4[tid] = s4[tid];
    d4[tid + 256] = s4[tid + 256];
  }
  __syncthreads();
  const int lr = tid >> 3, kc = tid & 7;     // 32 gate rows x 8 k-chunks
  const int q = lr >> 3, ci = lr & 7;        // gate q, local col ci
  const int grow = q * H_DIM + c0 + ci;
  const float* wrow = I.Whh + (size_t)grow * H_DIM;
  float a0 = 0.f, a1 = 0.f, a2 = 0.f, a3 = 0.f;
#pragma unroll
  for (int it = 0; it < 16; ++it) {
    const int k = it * 32 + kc * 4;
    const float4 w  = *(const float4*)(wrow + k);
    const float4 h0 = *(const float4*)&hs[0 * H_DIM + k];
    const float4 h1 = *(const float4*)&hs[1 * H_DIM + k];
    const float4 h2 = *(const float4*)&hs[2 * H_DIM + k];
    const float4 h3 = *(const float4*)&hs[3 * H_DIM + k];
    a0 += w.x * h0.x + w.y * h0.y + w.z * h0.z + w.w * h0.w;
    a1 += w.x * h1.x + w.y * h1.y + w.z * h1.z + w.w * h1.w;
    a2 += w.x * h2.x + w.y * h2.y + w.z * h2.z + w.w * h2.w;
    a3 += w.x * h3.x + w.y * h3.y + w.z * h3.z + w.w * h3.w;
  }
#pragma unroll
  for (int off = 1; off < 8; off <<= 1) {
    a0 += __shfl_xor(a0, off);
    a1 += __shfl_xor(a1, off);
    a2 += __shfl_xor(a2, off);
    a3 += __shfl_xor(a3, off);
  }
  if (kc == 0) {
    const float bb = I.bhh[grow];
    gred[lr][0] = a0 + I.xg[(size_t)(0 * S_LEN + t) * I.xg_stride + grow] + bb;
    gred[lr][1] = a1 + I.xg[(size_t)(1 * S_LEN + t) * I.xg_stride + grow] + bb;
    gred[lr][2] = a2 + I.xg[(size_t)(2 * S_LEN + t) * I.xg_stride + grow] + bb;
    gred[lr][3] = a3 + I.xg[(size_t)(3 * S_LEN + t) * I.xg_stride + grow] + bb;
  }
  __syncthreads();
  if (tid < 32) {
    const int b = tid & 3, cc = tid >> 2;
    const int col = c0 + cc;
    const float gi = gred[cc][b];
    const float gf = gred[8 + cc][b];
    const float gg = gred[16 + cc][b];
    const float go = gred[24 + cc][b];
    const float cold = I.c[b * H_DIM + col];
    const float cn = sigf(gf) * cold + sigf(gi) * tanhf(gg);
    const float hn = sigf(go) * tanhf(cn);
    I.c[b * H_DIM + col] = cn;
    I.h_out[b * H_DIM + col] = hn;
    if (I.spk)
      I.spk[(size_t)(b * S_LEN + t) * H_DIM + col] = (hn - I.thr[col]) > 0.f ? 1.f : 0.f;
  }
}

extern "C" void kernel_launch(void* const* d_in, const int* in_sizes, int n_in,
                              void* d_out, int out_size, void* d_ws, size_t ws_size,
                              hipStream_t stream) {
  (void)in_sizes; (void)n_in; (void)out_size; (void)ws_size;
  const int*   src       = (const int*)d_in[0];
  const int*   tgt       = (const int*)d_in[1];
  const float* emb_enc   = (const float*)d_in[2];
  const float* enc_alpha = (const float*)d_in[3];
  const float* enc_gamma = (const float*)d_in[4];
  const float* enc_beta  = (const float*)d_in[5];
  const float* enc_Wih   = (const float*)d_in[6];
  const float* enc_Whh   = (const float*)d_in[7];
  const float* enc_bih   = (const float*)d_in[8];
  const float* enc_bhh   = (const float*)d_in[9];
  const float* emb_dec   = (const float*)d_in[11];
  const float* dec_alpha = (const float*)d_in[12];
  const float* dec_gamma = (const float*)d_in[13];
  const float* dec_beta  = (const float*)d_in[14];
  const float* dec_Wih   = (const float*)d_in[15];
  const float* dec_Whh   = (const float*)d_in[16];
  const float* dec_bih   = (const float*)d_in[17];
  const float* dec_bhh   = (const float*)d_in[18];
  const float* dec_thr   = (const float*)d_in[19];
  const float* dec_fc_W  = (const float*)d_in[20];
  const float* dec_fc_b  = (const float*)d_in[21];
  const float* dyt_alpha = (const float*)d_in[22];
  const float* dyt_gamma = (const float*)d_in[23];
  const float* dyt_beta  = (const float*)d_in[24];
  const float* out_W     = (const float*)d_in[25];
  const float* out_b     = (const float*)d_in[26];
  float* out = (float*)d_out;

  float* ws     = (float*)d_ws;
  float* src_e  = ws;                       // [1024,512]
  float* dec_x0 = ws + 524288;              // [1024,512]
  float* dec_x1 = ws + 1048576;             // [1024,512]
  float* xg_enc = ws + 1572864;             // [1024,4096] both enc layers
  float* xg_dec = ws + 5767168;             // [1024,2048]
  float* spk    = ws + 7864320;             // [1024,512]
  float* st     = ws + 8388608;             // state block (16384 floats)
  float* enc_c0  = st;
  float* enc_c1  = st + 2048;
  float* enc_h0a = st + 4096;
  float* enc_h0b = st + 6144;
  float* enc_h1a = st + 8192;
  float* enc_h1b = st + 10240;
  float* dec_ha  = st + 12288;
  float* dec_hb  = st + 14336;

  zero_kernel<<<16, 256, 0, stream>>>(st, 4096);
  embed_dyt<<<1024, 128, 0, stream>>>(src, emb_enc, enc_alpha, enc_gamma, enc_beta, src_e);
  embed_dyt<<<1024, 128, 0, stream>>>(tgt, emb_dec, dec_alpha, dec_gamma, dec_beta, dec_x0);

  // Encoder xg for both layers at once: W stacked [4096,512]
  gemm_nt<0><<<dim3(8, 32), 256, 0, stream>>>(src_e, enc_Wih, enc_bih, xg_enc, 4096, 512,
                                              nullptr, nullptr, nullptr, nullptr);
  // Encoder recurrence: both layers per dispatch
  for (int t = 0; t < 256; ++t) {
    StepInst A, B;
    A.xg = xg_enc;          A.Whh = enc_Whh;                A.bhh = enc_bhh;
    A.c = enc_c0;
    A.h_in  = (t == 0) ? enc_h0a : ((t & 1) ? enc_h0b : enc_h0a);
    A.h_out = (t & 1) ? enc_h0a : enc_h0b;
    A.spk = nullptr; A.thr = nullptr; A.xg_stride = 4096;
    B.xg = xg_enc + 2048;   B.Whh = enc_Whh + 1048576;      B.bhh = enc_bhh + 2048;
    B.c = enc_c1;
    B.h_in  = (t == 0) ? enc_h1a : ((t & 1) ? enc_h1b : enc_h1a);
    B.h_out = (t & 1) ? enc_h1a : enc_h1b;
    B.spk = nullptr; B.thr = nullptr; B.xg_stride = 4096;
    slstm_step<<<128, 256, 0, stream>>>(A, B, t);
  }
  // final enc h is in enc_hXa (t=255 writes the 'a' buffer); c in enc_cX

  const float* xin = dec_x0;
  float* xout = dec_x1;
  for (int l = 0; l < 2; ++l) {
    gemm_nt<0><<<dim3(8, 16), 256, 0, stream>>>(xin, dec_Wih + (size_t)l * 1048576,
                                                dec_bih + l * 2048, xg_dec, 2048, 512,
                                                nullptr, nullptr, nullptr, nullptr);
    float* c  = (l == 0) ? enc_c0 : enc_c1;
    float* hf = (l == 0) ? enc_h0a : enc_h1a;
    for (int t = 0; t < 256; ++t) {
      StepInst D;
      D.xg = xg_dec; D.Whh = dec_Whh + (size_t)l * 1048576; D.bhh = dec_bhh + l * 2048;
      D.c = c;
      D.h_in  = (t == 0) ? hf : ((t & 1) ? dec_ha : dec_hb);
      D.h_out = (t & 1) ? dec_hb : dec_ha;
      D.spk = spk; D.thr = dec_thr + l * 512; D.xg_stride = 2048;
      slstm_step<<<64, 256, 0, stream>>>(D, D, t);
    }
    gemm_nt<1><<<dim3(8, 4), 256, 0, stream>>>(spk, dec_fc_W + (size_t)l * 262144,
                                               dec_fc_b + l * 512, xout, 512, 512,
                                               dyt_alpha + l, dyt_gamma + l * 512,
                                               dyt_beta + l * 512,
                                               (l > 0) ? xin : nullptr);
    const float* tmp = xin; xin = xout; xout = (float*)tmp;
  }

  gemm_nt<0><<<dim3(8, 250), 256, 0, stream>>>(xin, out_W, out_b, out, 32000, 512,
                                               nullptr, nullptr, nullptr, nullptr);
}